// Round 1
// baseline (61263.525 us; speedup 1.0000x reference)
//
#include <hip/hip_runtime.h>

// GreyBox rollout: T=65536 strictly-sequential steps.
//   f   = W2 @ tanh(W1 @ c + b1) + b2
//   c'  = A @ c + Bw @ w_t + u_t + DT*f
//   y_t = c'[obs_idx]
// Round 1: single persistent workgroup (256 thr), A/W1 rows in registers,
// c/h through LDS with 2 barriers/step, u/w via LDS ring prefetched 8 steps
// ahead. Latency-bound by design; this round establishes a correct baseline
// and the counter picture.

#define T_STEPS 65536
#define SD 100
#define NH 8
#define NOBS 12
#define DT_F 0.01f
#define PFD 16   // u/w ring depth (slots)
#define PF 8     // prefetch distance (steps ahead)

__global__ __launch_bounds__(256) void greybox_rollout(
    const float* __restrict__ c0, const float* __restrict__ w,
    const float* __restrict__ u, const float* __restrict__ A,
    const float* __restrict__ Bw, const float* __restrict__ W1,
    const float* __restrict__ b1, const float* __restrict__ W2,
    const float* __restrict__ b2, const int* __restrict__ obs_idx,
    float* __restrict__ out_c, float* __restrict__ out_y)
{
    // c stored split: c[0..49] at [0..49], c[50..99] at [64..113] (16B-aligned halves)
    __shared__ float c_buf[128];
    __shared__ float h_buf[8];
    __shared__ float u_ring[PFD][SD];
    __shared__ float w_ring[PFD][2];

    const int tid = threadIdx.x;
    const bool is_arow = tid < 200;                      // A rows, 2 thr/row
    const bool is_h    = (tid >= 200) && (tid < 216);    // W1 rows, 2 thr/row
    const bool is_dot  = tid < 216;
    const bool is_y    = (tid >= 216) && (tid < 228);
    const bool is_upf  = (tid >= 228) && (tid < 253);    // 25 thr: one float4 of u each
    const bool is_wpf  = (tid == 253);

    int row = 0, half = 0;
    float wreg[50];          // my half-row of A (or W1)
    float W2r[8];
    float bw0 = 0.f, bw1 = 0.f, b2r = 0.f, b1k = 0.f;

    if (is_arow) {
        row = tid >> 1; half = tid & 1;
        #pragma unroll
        for (int j = 0; j < 50; ++j) wreg[j] = A[row * SD + half * 50 + j];
        #pragma unroll
        for (int k = 0; k < 8; ++k) W2r[k] = W2[row * NH + k];
        bw0 = Bw[row * 2 + 0]; bw1 = Bw[row * 2 + 1]; b2r = b2[row];
    } else if (is_h) {
        row = (tid - 200) >> 1; half = (tid - 200) & 1;
        #pragma unroll
        for (int j = 0; j < 50; ++j) wreg[j] = W1[row * SD + half * 50 + j];
        b1k = b1[row];
    }

    int ypos = 0;
    if (is_y) {
        int idx = obs_idx[tid - 216];
        ypos = (idx < 50) ? idx : (64 + idx - 50);
    }
    const int cpos = (row < 50) ? row : (64 + row - 50);

    if (tid < SD) {
        int pos = (tid < 50) ? tid : (64 + tid - 50);
        c_buf[pos] = c0[tid];
    }
    // preload ring with steps 0..PF-1
    if (is_upf) {
        const int i4 = tid - 228;
        #pragma unroll
        for (int p = 0; p < PF; ++p)
            ((float4*)(&u_ring[p][0]))[i4] = ((const float4*)(u + p * SD))[i4];
    }
    if (is_wpf) {
        #pragma unroll
        for (int p = 0; p < PF; ++p) {
            w_ring[p][0] = w[2 * p];
            w_ring[p][1] = w[2 * p + 1];
        }
    }

    for (int t = 0; t < T_STEPS; ++t) {
        __syncthreads();                          // barrier 1: c_buf = c[t-1]

        // y for the previous step (c_buf finalized at last step's epilogue)
        if (is_y && t > 0) out_y[(t - 1) * NOBS + (tid - 216)] = c_buf[ypos];

        // issue prefetch loads for step t+PF (consumed PF steps later)
        const int pt = t + PF;
        const bool do_pf = pt < T_STEPS;
        float4 pfv = {0.f, 0.f, 0.f, 0.f};
        float pfw0 = 0.f, pfw1 = 0.f;
        if (is_upf && do_pf) pfv = ((const float4*)(u + pt * SD))[tid - 228];
        if (is_wpf && do_pf) { pfw0 = w[2 * pt]; pfw1 = w[2 * pt + 1]; }

        // 50-FMA half-row dot over c (identical code path for A-rows and W1-rows)
        float acc = 0.f;
        if (is_dot) {
            const float* cb = &c_buf[half * 64];
            #pragma unroll
            for (int i = 0; i < 12; ++i) {
                float4 c4 = ((const float4*)cb)[i];
                acc = fmaf(wreg[4 * i + 0], c4.x, acc);
                acc = fmaf(wreg[4 * i + 1], c4.y, acc);
                acc = fmaf(wreg[4 * i + 2], c4.z, acc);
                acc = fmaf(wreg[4 * i + 3], c4.w, acc);
            }
            acc = fmaf(wreg[48], cb[48], acc);
            acc = fmaf(wreg[49], cb[49], acc);
            acc += __shfl_xor(acc, 1);            // combine the two halves
        }
        if (is_h) {
            float hv = tanhf(acc + b1k);
            if (half == 0) h_buf[row] = hv;
        }

        __syncthreads();                          // barrier 2: h_buf ready

        if (is_arow) {
            const float4 h0 = ((const float4*)h_buf)[0];
            const float4 h1 = ((const float4*)h_buf)[1];
            float fd = b2r;
            fd = fmaf(W2r[0], h0.x, fd);
            fd = fmaf(W2r[1], h0.y, fd);
            fd = fmaf(W2r[2], h0.z, fd);
            fd = fmaf(W2r[3], h0.w, fd);
            fd = fmaf(W2r[4], h1.x, fd);
            fd = fmaf(W2r[5], h1.y, fd);
            fd = fmaf(W2r[6], h1.z, fd);
            fd = fmaf(W2r[7], h1.w, fd);
            const int slot = t & (PFD - 1);
            float cn = acc + bw0 * w_ring[slot][0] + bw1 * w_ring[slot][1]
                     + u_ring[slot][row] + DT_F * fd;
            if (half == 0) {
                c_buf[cpos] = cn;                 // state for next step
                out_c[(size_t)t * SD + row] = cn; // fire-and-forget store
            }
        }

        // land the prefetched data into its ring slot (slot (t+8)&15 != t&15)
        if (is_upf && do_pf) ((float4*)(&u_ring[pt & (PFD - 1)][0]))[tid - 228] = pfv;
        if (is_wpf && do_pf) {
            w_ring[pt & (PFD - 1)][0] = pfw0;
            w_ring[pt & (PFD - 1)][1] = pfw1;
        }
    }

    __syncthreads();
    if (is_y) out_y[(size_t)(T_STEPS - 1) * NOBS + (tid - 216)] = c_buf[ypos];
}

extern "C" void kernel_launch(void* const* d_in, const int* in_sizes, int n_in,
                              void* d_out, int out_size, void* d_ws, size_t ws_size,
                              hipStream_t stream) {
    const float* c0 = (const float*)d_in[0];
    const float* w  = (const float*)d_in[1];
    const float* u  = (const float*)d_in[2];
    const float* A  = (const float*)d_in[3];
    const float* Bw = (const float*)d_in[4];
    const float* W1 = (const float*)d_in[5];
    const float* b1 = (const float*)d_in[6];
    const float* W2 = (const float*)d_in[7];
    const float* b2 = (const float*)d_in[8];
    const int* obs  = (const int*)d_in[9];
    float* out_c = (float*)d_out;
    float* out_y = out_c + (size_t)T_STEPS * SD;

    hipLaunchKernelGGL(greybox_rollout, dim3(1), dim3(256), 0, stream,
                       c0, w, u, A, Bw, W1, b1, W2, b2, obs, out_c, out_y);
}

// Round 2
// 41393.945 us; speedup vs baseline: 1.4800x; 1.4800x over previous
//
#include <hip/hip_runtime.h>
#include <math.h>

// GreyBox rollout, round 2.
//   h[s] = tanh(W1 c[s-1] + b1),  c[s] = A c[s-1] + Bw w[s] + u[s] + DT (W2 h[s] + b2)
// Key restructure vs round 1 (61 ms, all barrier-drain stall):
//  * NO global memory ops inside the per-step loop (the __syncthreads vmcnt(0)
//    drain was serializing ~900cy of HBM latency per step). u/w staged into LDS
//    and c staged out of LDS once per 64-step chunk.
//  * ONE barrier per step (was 2): z[s+1] = (W1A) c[s-1] + W1 d[s] + DT (W1W2) h[s] + b1
//    lets the tanh chain (wave 3) run in PARALLEL with the A·c update (waves 0-2),
//    both reading only c[s-1] and h[s].
//  * pair/quad combines via DPP quad_perm (VALU latency) instead of __shfl (LDS pipe).

#define T_STEPS 65536
#define SD 100
#define KCH 64
#define NCHUNK (T_STEPS / KCH)
#define DT_F 0.01f

__device__ __forceinline__ float dpp_xor1_add(float x) {
  int v = __builtin_amdgcn_update_dpp(0, __float_as_int(x), 0xB1, 0xF, 0xF, true); // quad_perm(1,0,3,2)
  return x + __int_as_float(v);
}
__device__ __forceinline__ float dpp_xor2_add(float x) {
  int v = __builtin_amdgcn_update_dpp(0, __float_as_int(x), 0x4E, 0xF, 0xF, true); // quad_perm(2,3,0,1)
  return x + __int_as_float(v);
}
__device__ __forceinline__ float fast_tanh(float x) {
  float ax = fabsf(x);
  float e2 = __builtin_amdgcn_exp2f(ax * -2.885390081777927f);  // e^{-2|x|}
  float r = (1.f - e2) / (1.f + e2);
  return copysignf(r, x);
}

__global__ __launch_bounds__(256, 1) void greybox_rollout(
    const float* __restrict__ c0, const float* __restrict__ w,
    const float* __restrict__ u, const float* __restrict__ A,
    const float* __restrict__ Bw, const float* __restrict__ W1,
    const float* __restrict__ b1, const float* __restrict__ W2,
    const float* __restrict__ b2, const int* __restrict__ obs_idx,
    float* __restrict__ out_c, float* __restrict__ out_y)
{
  // c_chunk doubles as the state ring (row t&63 = c[s]) and the output stage.
  __shared__ __align__(16) float c_chunk[KCH * SD];
  __shared__ __align__(16) float u_chunk[KCH * SD];
  __shared__ __align__(16) float w_chunk[KCH * 2];
  __shared__ __align__(16) float h_buf[2][8];
  __shared__ int obs_pos[12];

  const int tid = threadIdx.x;

  // --- roles -------------------------------------------------------------
  // waves 0-2 (tid 0..191): A rows 0..95, 2 threads/row (halves via 13
  //   overlapping float4 blocks with zero-padded weights; combine via DPP xor1).
  // wave 3 (tid 192..239): 12 "quad rows" x 4 threads (quarter-dots over 25
  //   float4 blocks, combine via DPP xor1+xor2):
  //     ridx 0..7  -> z rows: z[s+1] = W1A·c[s-1] + W1·u[s] + small; h=tanh(z)
  //     ridx 8..11 -> A rows 96..99 (same dot shape, w1q=0)
  // tid 240..255: idle in the step loop, help in flush.
  const bool isA2 = tid < 192;
  const bool isW3 = (tid >= 192) && (tid < 240);
  const int row  = tid >> 1;        // isA2
  const int half = tid & 1;
  const int ridx = (tid - 192) >> 2;  // isW3
  const int q    = tid & 3;           // 192 % 4 == 0 -> quad aligned
  const bool isZ = isW3 && (ridx < 8);
  const int zr   = ridx;
  const int arow = 96 + ridx - 8;

  // --- per-thread weight registers ---------------------------------------
  float aW[52];               // isA2: my half-row of A (zero-padded overlap)
  float w2h0 = 0.f, w2h1 = 0.f, w2h2 = 0.f, w2h3 = 0.f;  // isA2: DT*W2[row][half*4+..]
  float bw0 = 0.f, bw1 = 0.f, cst = 0.f;                  // isA2 half0
  float wq[28], w1q[28];      // isW3: quarter weights (c-dot / u-dot)
  float ht_a = 0.f, ht_b = 0.f;  // isW3: h-term weights (DT-scaled)
  float smc = 0.f, smw0 = 0.f, smw1 = 0.f, b1r = 0.f;     // isW3 q0 small terms

  if (isA2) {
    // half0 covers c floats 0..51 (weights A[row][0..49],0,0);
    // half1 covers c floats 48..99 (weights 0,0,A[row][50..99]).
    #pragma unroll
    for (int j = 0; j < 52; ++j) {
      int col = half * 48 + j;
      bool valid = half ? (j >= 2) : (j < 50);
      aW[j] = valid ? A[row * SD + col] : 0.f;
    }
    w2h0 = DT_F * W2[row * 8 + half * 4 + 0];
    w2h1 = DT_F * W2[row * 8 + half * 4 + 1];
    w2h2 = DT_F * W2[row * 8 + half * 4 + 2];
    w2h3 = DT_F * W2[row * 8 + half * 4 + 3];
    if (half == 0) {
      bw0 = Bw[row * 2 + 0];
      bw1 = Bw[row * 2 + 1];
      cst = DT_F * b2[row];
    }
  }

  if (isW3) {
    // element blocks for quarter q: float offsets 4q+16*jb, jb=0..6, clamped
    // to 96 (duplicate block with zero weight -> no OOB, no NaN poison).
    #pragma unroll
    for (int jb = 0; jb < 7; ++jb) {
      int off = 4 * q + 16 * jb; bool dup = off > 96; if (dup) off = 96;
      #pragma unroll
      for (int m = 0; m < 4; ++m) {
        float wv = 0.f, w1v = 0.f;
        if (!dup) {
          if (isZ) w1v = W1[zr * SD + off + m];
          else     wv  = A[arow * SD + off + m];
        }
        wq[4 * jb + m] = wv;
        w1q[4 * jb + m] = w1v;
      }
    }
    if (isZ) {
      // wq <- (W1 @ A) row-quarter; plus all small-term precomputes.
      float hta = 0.f, htb = 0.f, w1b2 = 0.f, wb0 = 0.f, wb1 = 0.f;
      for (int k = 0; k < SD; ++k) {
        float w1k = W1[zr * SD + k];
        const float* Ar = A + k * SD;
        #pragma unroll
        for (int jb = 0; jb < 7; ++jb) {
          int off = 4 * q + 16 * jb; if (off > 96) off = 96;
          #pragma unroll
          for (int m = 0; m < 4; ++m)
            wq[4 * jb + m] = fmaf(w1k, Ar[off + m], wq[4 * jb + m]);
        }
        hta  = fmaf(w1k, W2[k * 8 + 2 * q], hta);
        htb  = fmaf(w1k, W2[k * 8 + 2 * q + 1], htb);
        w1b2 = fmaf(w1k, b2[k], w1b2);
        wb0  = fmaf(w1k, Bw[k * 2 + 0], wb0);
        wb1  = fmaf(w1k, Bw[k * 2 + 1], wb1);
      }
      // zero the duplicated clamp blocks (they accumulated garbage-free but
      // nonzero W1A values that would double-count element block 24)
      #pragma unroll
      for (int jb = 0; jb < 7; ++jb) {
        if (4 * q + 16 * jb > 96) {
          #pragma unroll
          for (int m = 0; m < 4; ++m) wq[4 * jb + m] = 0.f;
        }
      }
      ht_a = DT_F * hta;
      ht_b = DT_F * htb;
      b1r  = b1[zr];
      smc  = b1r + DT_F * w1b2;   // b1 + DT*(W1@b2)
      smw0 = wb0; smw1 = wb1;     // W1@Bw columns
    } else {
      ht_a = DT_F * W2[arow * 8 + 2 * q];
      ht_b = DT_F * W2[arow * 8 + 2 * q + 1];
      smc  = DT_F * b2[arow];
      smw0 = Bw[arow * 2 + 0];
      smw1 = Bw[arow * 2 + 1];
    }
  }

  // --- stage chunk 0 + init state ---------------------------------------
  for (int i = tid; i < (KCH * SD) / 4; i += 256)
    ((float4*)u_chunk)[i] = ((const float4*)u)[i];
  if (tid < KCH * 2) w_chunk[tid] = w[tid];
  if (tid < SD) c_chunk[63 * SD + tid] = c0[tid];   // ring slot for c[-1]
  if (tid < 12) obs_pos[tid] = obs_idx[tid];
  __syncthreads();

  // bootstrap h[0] = tanh(W1 c0 + b1)
  if (isZ) {
    float p0 = 0.f, p1 = 0.f, p2 = 0.f, p3 = 0.f;
    const float* cp = c_chunk + 63 * SD;
    #pragma unroll
    for (int jb = 0; jb < 7; ++jb) {
      int off = 4 * q + 16 * jb; if (off > 96) off = 96;
      float4 c4 = *(const float4*)(cp + off);
      p0 = fmaf(w1q[4 * jb + 0], c4.x, p0);
      p1 = fmaf(w1q[4 * jb + 1], c4.y, p1);
      p2 = fmaf(w1q[4 * jb + 2], c4.z, p2);
      p3 = fmaf(w1q[4 * jb + 3], c4.w, p3);
    }
    float acc = (p0 + p1) + (p2 + p3);
    acc = dpp_xor1_add(acc);
    acc = dpp_xor2_add(acc);
    float hv = fast_tanh(acc + b1r);
    if (q == 0) h_buf[0][zr] = hv;
  }

  // --- main loop ----------------------------------------------------------
  for (int k = 0; k < NCHUNK; ++k) {
    const int s0 = k * KCH;

    #pragma unroll 2
    for (int t = 0; t < KCH; ++t) {
      __syncthreads();   // c[s-1] (ring) and h[s] visible; LDS-only drain

      const float* cprev = c_chunk + ((t + 63) & 63) * SD;

      if (isA2) {
        const float4* cb = (const float4*)cprev + half * 12;
        float p0 = 0.f, p1 = 0.f, p2 = 0.f, p3 = 0.f;
        #pragma unroll
        for (int i = 0; i < 13; ++i) {
          float4 c4 = cb[i];
          p0 = fmaf(aW[4 * i + 0], c4.x, p0);
          p1 = fmaf(aW[4 * i + 1], c4.y, p1);
          p2 = fmaf(aW[4 * i + 2], c4.z, p2);
          p3 = fmaf(aW[4 * i + 3], c4.w, p3);
        }
        float4 h4 = *(const float4*)(&h_buf[t & 1][half * 4]);
        float acc = (p0 + p1) + (p2 + p3);
        acc = fmaf(w2h0, h4.x, acc);
        acc = fmaf(w2h1, h4.y, acc);
        acc = fmaf(w2h2, h4.z, acc);
        acc = fmaf(w2h3, h4.w, acc);
        if (half == 0) {
          float2 wv = *(const float2*)(&w_chunk[t * 2]);
          acc += cst + bw0 * wv.x + bw1 * wv.y + u_chunk[t * SD + row];
        }
        acc = dpp_xor1_add(acc);
        if (half == 0) c_chunk[t * SD + row] = acc;
      } else if (isW3) {
        const float* ut = u_chunk + t * SD;
        float p0 = 0.f, p1 = 0.f, p2 = 0.f, p3 = 0.f;
        #pragma unroll
        for (int jb = 0; jb < 7; ++jb) {
          int off = 4 * q + 16 * jb; if (off > 96) off = 96;
          float4 c4 = *(const float4*)(cprev + off);
          float4 u4 = *(const float4*)(ut + off);
          p0 = fmaf(wq[4 * jb + 0], c4.x, p0);
          p1 = fmaf(wq[4 * jb + 1], c4.y, p1);
          p2 = fmaf(wq[4 * jb + 2], c4.z, p2);
          p3 = fmaf(wq[4 * jb + 3], c4.w, p3);
          p0 = fmaf(w1q[4 * jb + 0], u4.x, p0);
          p1 = fmaf(w1q[4 * jb + 1], u4.y, p1);
          p2 = fmaf(w1q[4 * jb + 2], u4.z, p2);
          p3 = fmaf(w1q[4 * jb + 3], u4.w, p3);
        }
        float2 h2 = *(const float2*)(&h_buf[t & 1][2 * q]);
        float acc = (p0 + p1) + (p2 + p3);
        acc = fmaf(ht_a, h2.x, acc);
        acc = fmaf(ht_b, h2.y, acc);
        if (q == 0) {
          float2 wv = *(const float2*)(&w_chunk[t * 2]);
          float ex = smc + smw0 * wv.x + smw1 * wv.y;
          if (!isZ) ex += u_chunk[t * SD + arow];
          acc += ex;
        }
        acc = dpp_xor1_add(acc);
        acc = dpp_xor2_add(acc);
        if (isZ) {
          float hv = fast_tanh(acc);
          if (q == 0) h_buf[(t + 1) & 1][zr] = hv;
        } else if (q == 0) {
          c_chunk[t * SD + arow] = acc;
        }
      }
    }

    __syncthreads();   // all 64 c rows of this chunk finalized

    // flush c -> out_c (contiguous), gather y, stage next u/w chunk.
    for (int i = tid; i < (KCH * SD) / 4; i += 256) {
      float4 v = ((const float4*)c_chunk)[i];
      ((float4*)(out_c + (size_t)s0 * SD))[i] = v;
    }
    for (int e = tid; e < KCH * 12; e += 256) {
      int sl = e / 12, j = e - sl * 12;
      out_y[(size_t)(s0 + sl) * 12 + j] = c_chunk[sl * SD + obs_pos[j]];
    }
    if (k + 1 < NCHUNK) {
      const float* unext = u + (size_t)(s0 + KCH) * SD;
      for (int i = tid; i < (KCH * SD) / 4; i += 256)
        ((float4*)u_chunk)[i] = ((const float4*)unext)[i];
      if (tid < KCH * 2) w_chunk[tid] = w[(size_t)(s0 + KCH) * 2 + tid];
    }
    // next iteration's first __syncthreads orders these against step reads
  }
}

extern "C" void kernel_launch(void* const* d_in, const int* in_sizes, int n_in,
                              void* d_out, int out_size, void* d_ws, size_t ws_size,
                              hipStream_t stream) {
  const float* c0 = (const float*)d_in[0];
  const float* w  = (const float*)d_in[1];
  const float* u  = (const float*)d_in[2];
  const float* A  = (const float*)d_in[3];
  const float* Bw = (const float*)d_in[4];
  const float* W1 = (const float*)d_in[5];
  const float* b1 = (const float*)d_in[6];
  const float* W2 = (const float*)d_in[7];
  const float* b2 = (const float*)d_in[8];
  const int* obs  = (const int*)d_in[9];
  float* out_c = (float*)d_out;
  float* out_y = out_c + (size_t)T_STEPS * SD;

  hipLaunchKernelGGL(greybox_rollout, dim3(1), dim3(256), 0, stream,
                     c0, w, u, A, Bw, W1, b1, W2, b2, obs, out_c, out_y);
}

// Round 3
// 18846.828 us; speedup vs baseline: 3.2506x; 2.1963x over previous
//
#include <hip/hip_runtime.h>
#include <math.h>

// GreyBox rollout, round 3: decouple the 8-dim nonlinear chain from the
// 100-dim linear state.
//   c[t] = A c[t-1] + d[t] + DT*W2 h[t],  d[t] = Bw w[t] + u[t] + DT*b2
//   h[t] = tanh(W1 c[t-1] + b1)
// Exact split: c = L + DT*rho, L = linear rollout (parallel 3-phase scan over
// 256 chunks of 256 steps), rho[t] = sum_j A^(t-j) W2 h[j].
// z[t] = q[t] + DT*W1 rho[t-1], q[t] = W1 L[t-1] + b1 (precomputed).
// Sequential core (k4): one workgroup; per 8-step block:
//   wave0: quad lanes 0-3 run the h-chain (G0 = W1W2 in regs, h all-gather via
//          DPP quad_perm); lanes 8-63 accumulate lags 1..14 via G_k into an
//          LDS z-window (same wave -> lockstep, no intra-block barriers);
//          lanes 4-7 flush h of the previous block to global.
//   waves1&3: advance r = rho at block granularity (A^8 rows in registers).
//   waves2: build z-base for block m+1 = q + P_{16+j}*r_{m-1} + G-terms of
//          block m-1's h. One barrier per 8 steps.
// Then rho is re-rolled in parallel (3-phase scan driven by W2 h) and
// c = L + DT*rho, y = c[obs].

#define T_STEPS 65536
#define SD 100
#define DT_F 0.01f

// ---------- helpers ----------
__device__ __forceinline__ float dpp_xor1_add(float x) {
  int v = __builtin_amdgcn_update_dpp(0, __float_as_int(x), 0xB1, 0xF, 0xF, true);
  return x + __int_as_float(v);
}
template <int PAT>
__device__ __forceinline__ float dppq(float x) {
  return __int_as_float(__builtin_amdgcn_update_dpp(0, __float_as_int(x), PAT, 0xF, 0xF, true));
}
__device__ __forceinline__ float tanh_fast(float x) {
  // tanh(x) = 1 - 2/(e^{2x}+1);  e^{2x} = exp2(x * 2/ln2)
  float e = __builtin_amdgcn_exp2f(x * 2.885390081777927f);
  return 1.f - 2.f * __builtin_amdgcn_rcpf(e + 1.f);
}

// ---------- K0: setup (A^8, A^256, P_k=DT*W1A^k (k=16..23), G_k=DT*W1A^kW2
// (k=0..22), Q_i=A^{7-i}W2) ----------
__global__ __launch_bounds__(256, 1) void k0_setup(
    const float* __restrict__ A, const float* __restrict__ W1,
    const float* __restrict__ W2, float* __restrict__ A8o,
    float* __restrict__ A256o, float* __restrict__ Pws,
    float* __restrict__ Gws, float* __restrict__ Qws) {
  __shared__ __align__(16) float Al[10000];
  __shared__ __align__(16) float M0[10000];
  __shared__ __align__(16) float M1[10000];
  __shared__ __align__(16) float Pb[2][800];
  __shared__ __align__(16) float Vb[2][800];
  const int tid = threadIdx.x;
  for (int i = tid; i < 2500; i += 256) {
    ((float4*)Al)[i] = ((const float4*)A)[i];
    ((float4*)M0)[i] = ((const float4*)A)[i];
  }
  __syncthreads();
  // squarings: after s, result in ((s&1)?M0:M1). s=2 -> A^8, s=7 -> A^256.
  for (int s = 0; s < 8; ++s) {
    const float* src = (s & 1) ? M1 : M0;
    float* dst = (s & 1) ? M0 : M1;
    if (tid < 100) {
      float4 acc[25];
      #pragma unroll
      for (int i = 0; i < 25; ++i) acc[i] = make_float4(0.f, 0.f, 0.f, 0.f);
      for (int k = 0; k < 100; ++k) {
        float a = src[tid * 100 + k];
        const float4* rk = (const float4*)(src + k * 100);
        #pragma unroll
        for (int i = 0; i < 25; ++i) {
          float4 r4 = rk[i];
          acc[i].x = fmaf(a, r4.x, acc[i].x);
          acc[i].y = fmaf(a, r4.y, acc[i].y);
          acc[i].z = fmaf(a, r4.z, acc[i].z);
          acc[i].w = fmaf(a, r4.w, acc[i].w);
        }
      }
      #pragma unroll
      for (int i = 0; i < 25; ++i) ((float4*)(dst + tid * 100))[i] = acc[i];
    }
    __syncthreads();
    if (s == 2) for (int i = tid; i < 2500; i += 256) ((float4*)A8o)[i] = ((const float4*)dst)[i];
    if (s == 7) for (int i = tid; i < 2500; i += 256) ((float4*)A256o)[i] = ((const float4*)dst)[i];
    __syncthreads();
  }
  // P chain: P_0 = W1; P_k = P_{k-1} A. Store G_k (k<=22), P_k (16<=k<=23).
  for (int i = tid; i < 800; i += 256) Pb[0][i] = W1[i];
  __syncthreads();
  for (int k = 0; k < 24; ++k) {
    const float* Pc = Pb[k & 1];
    if (k <= 22 && tid < 64) {
      int i = tid >> 3, c = tid & 7;
      float g = 0.f;
      for (int l = 0; l < 100; ++l) g = fmaf(Pc[i * 100 + l], W2[l * 8 + c], g);
      Gws[k * 64 + i * 8 + c] = DT_F * g;
    }
    if (k >= 16) for (int i = tid; i < 800; i += 256) Pws[(k - 16) * 800 + i] = DT_F * Pc[i];
    __syncthreads();
    if (k < 23) {
      float* Pn = Pb[(k + 1) & 1];
      if (tid < 64) {
        int i = tid >> 3, cg = tid & 7;
        int c0 = cg * 13, c1 = c0 + 13 < 100 ? c0 + 13 : 100;
        for (int c = c0; c < c1; ++c) {
          float v = 0.f;
          for (int l = 0; l < 100; ++l) v = fmaf(Pc[i * 100 + l], Al[l * 100 + c], v);
          Pn[i * 100 + c] = v;
        }
      }
    }
    __syncthreads();
  }
  // V chain: V_0 = W2; V_j = A V_{j-1}. Q_i = V_{7-i} (unscaled).
  for (int i = tid; i < 800; i += 256) Vb[0][i] = W2[i];
  __syncthreads();
  for (int j = 0; j < 8; ++j) {
    const float* Vc = Vb[j & 1];
    for (int i = tid; i < 800; i += 256) Qws[(7 - j) * 800 + i] = Vc[i];
    __syncthreads();
    if (j < 7 && tid < 100) {
      float acc[8];
      #pragma unroll
      for (int c = 0; c < 8; ++c) acc[c] = 0.f;
      for (int l = 0; l < 100; ++l) {
        float av = Al[tid * 100 + l];
        #pragma unroll
        for (int c = 0; c < 8; ++c) acc[c] = fmaf(av, Vc[l * 8 + c], acc[c]);
      }
      float* dst = Vb[(j + 1) & 1] + tid * 8;
      #pragma unroll
      for (int c = 0; c < 8; ++c) dst[c] = acc[c];
    }
    __syncthreads();
  }
}

// ---------- rollout kernel (4 modes) ----------
// MODE 0: LIN local  (init 0, d = Bw w + u + DT b2)      -> SendOut
// MODE 1: LIN fix    (init X[b])                          -> out L, qbuf
// MODE 2: RHO local  (init 0, d = W2 h)                   -> SendOut
// MODE 3: RHO fix    (init XR[b])                         -> c = L+DT*rho, y
template <int MODE>
__global__ __launch_bounds__(256, 1) void k_rollout(
    const float* __restrict__ Amat, const float* __restrict__ Bw,
    const float* __restrict__ b2v, const float* __restrict__ ug,
    const float* __restrict__ wg, const float* __restrict__ W2,
    const float* __restrict__ hbufg, const float* __restrict__ W1,
    const float* __restrict__ b1v, const float* __restrict__ c0,
    const float* __restrict__ Xin, float* __restrict__ SendOut,
    float* __restrict__ Lc, float* __restrict__ qbuf,
    const int* __restrict__ obs, float* __restrict__ out_y) {
  __shared__ __align__(16) float cc[64 * 100];
  __shared__ __align__(16) float uc[64 * 100];
  __shared__ __align__(16) float wc[64 * 2];
  __shared__ __align__(16) float hc[64 * 8];
  __shared__ float W1l[800];
  __shared__ float b1l[8];
  __shared__ int obsl[12];
  const int tid = threadIdx.x;
  const int blk = blockIdx.x;
  const int base = blk * 256;
  const int row = tid >> 1, half = tid & 1;
  float aW[52];
  float w2h0 = 0.f, w2h1 = 0.f, w2h2 = 0.f, w2h3 = 0.f;
  float bw0 = 0.f, bw1 = 0.f, cst = 0.f;
  if (tid < 200) {
    #pragma unroll
    for (int j = 0; j < 52; ++j) {
      int col = half * 48 + j;
      bool valid = half ? (j >= 2) : (j < 50);
      aW[j] = valid ? Amat[row * SD + col] : 0.f;
    }
    if (MODE >= 2) {
      w2h0 = W2[row * 8 + half * 4 + 0];
      w2h1 = W2[row * 8 + half * 4 + 1];
      w2h2 = W2[row * 8 + half * 4 + 2];
      w2h3 = W2[row * 8 + half * 4 + 3];
    } else if (half == 0) {
      bw0 = Bw[row * 2 + 0];
      bw1 = Bw[row * 2 + 1];
      cst = DT_F * b2v[row];
    }
  }
  if (MODE == 1) {
    for (int i = tid; i < 800; i += 256) W1l[i] = W1[i];
    if (tid < 8) b1l[tid] = b1v[tid];
  }
  if (MODE == 3 && tid < 12) obsl[tid] = obs[tid];
  if (tid < SD) {
    float v = 0.f;
    if (MODE == 1 || MODE == 3) v = Xin[blk * SD + tid];
    cc[63 * SD + tid] = v;
  }
  if (MODE == 1 && blk == 0 && tid < 8) {
    float q0 = b1v[tid];
    for (int l = 0; l < SD; ++l) q0 = fmaf(W1[tid * SD + l], c0[l], q0);
    qbuf[tid] = q0;
  }

  for (int kk = 0; kk < 4; ++kk) {
    __syncthreads();
    if (MODE < 2) {
      const float* us = ug + (size_t)(base + kk * 64) * SD;
      for (int i = tid; i < 1600; i += 256) ((float4*)uc)[i] = ((const float4*)us)[i];
      if (tid < 128) wc[tid] = wg[(size_t)(base + kk * 64) * 2 + tid];
    } else {
      const float* hs = hbufg + (size_t)(base + kk * 64) * 8;
      for (int i = tid; i < 128; i += 256) ((float4*)hc)[i] = ((const float4*)hs)[i];
    }
    for (int t = 0; t < 64; ++t) {
      __syncthreads();
      const float* cprev = cc + ((t + 63) & 63) * SD;
      if (tid < 200) {
        const float4* cb = (const float4*)cprev + half * 12;
        float p0 = 0.f, p1 = 0.f, p2 = 0.f, p3 = 0.f;
        #pragma unroll
        for (int i = 0; i < 13; ++i) {
          float4 c4 = cb[i];
          p0 = fmaf(aW[4 * i + 0], c4.x, p0);
          p1 = fmaf(aW[4 * i + 1], c4.y, p1);
          p2 = fmaf(aW[4 * i + 2], c4.z, p2);
          p3 = fmaf(aW[4 * i + 3], c4.w, p3);
        }
        float acc = (p0 + p1) + (p2 + p3);
        if (MODE >= 2) {
          float4 h4 = *(const float4*)(hc + t * 8 + half * 4);
          acc = fmaf(w2h0, h4.x, acc);
          acc = fmaf(w2h1, h4.y, acc);
          acc = fmaf(w2h2, h4.z, acc);
          acc = fmaf(w2h3, h4.w, acc);
        } else if (half == 0) {
          float2 wv = *(const float2*)(wc + t * 2);
          acc += cst + bw0 * wv.x + bw1 * wv.y + uc[t * SD + row];
        }
        acc = dpp_xor1_add(acc);
        if (half == 0) cc[t * SD + row] = acc;
      }
    }
    __syncthreads();
    if (MODE == 1) {
      float4* Ld = (float4*)(Lc + (size_t)(base + kk * 64) * SD);
      for (int i = tid; i < 1600; i += 256) Ld[i] = ((const float4*)cc)[i];
      for (int e = tid; e < 512; e += 256) {
        int sl = e >> 3, zr = e & 7;
        float qv = b1l[zr];
        const float4* crow = (const float4*)(cc + sl * SD);
        const float* wr = W1l + zr * SD;
        #pragma unroll
        for (int i = 0; i < 25; ++i) {
          float4 c4 = crow[i];
          qv = fmaf(wr[4 * i + 0], c4.x, qv);
          qv = fmaf(wr[4 * i + 1], c4.y, qv);
          qv = fmaf(wr[4 * i + 2], c4.z, qv);
          qv = fmaf(wr[4 * i + 3], c4.w, qv);
        }
        qbuf[(size_t)(base + kk * 64 + sl + 1) * 8 + zr] = qv;
      }
    } else if (MODE == 3) {
      for (int e = tid; e < 768; e += 256) {
        int sl = e / 12, j = e - sl * 12;
        int tg = base + kk * 64 + sl;
        out_y[(size_t)tg * 12 + j] =
            Lc[(size_t)tg * SD + obsl[j]] + DT_F * cc[sl * SD + obsl[j]];
      }
      __syncthreads();
      float4* Ld = (float4*)(Lc + (size_t)(base + kk * 64) * SD);
      for (int i = tid; i < 1600; i += 256) {
        float4 L4 = Ld[i];
        float4 r4 = ((const float4*)cc)[i];
        L4.x = fmaf(DT_F, r4.x, L4.x);
        L4.y = fmaf(DT_F, r4.y, L4.y);
        L4.z = fmaf(DT_F, r4.z, L4.z);
        L4.w = fmaf(DT_F, r4.w, L4.w);
        Ld[i] = L4;
      }
    }
  }
  if (MODE == 0 || MODE == 2) {
    __syncthreads();
    if (tid < 25)
      ((float4*)(SendOut + blk * SD))[tid] = ((const float4*)(cc + 63 * SD))[tid];
  }
}

// ---------- scan: X[b+1] = A256 X[b] + Send[b] ----------
__global__ __launch_bounds__(256, 1) void k_scan(
    const float* __restrict__ A256, const float* __restrict__ Send,
    const float* __restrict__ c0, int use_c0, float* __restrict__ Xout) {
  __shared__ __align__(16) float X[256][100];
  __shared__ __align__(16) float sc[64 * 100];
  const int tid = threadIdx.x;
  const int row = tid >> 1, half = tid & 1;
  float aW[52];
  if (tid < 200) {
    #pragma unroll
    for (int j = 0; j < 52; ++j) {
      int col = half * 48 + j;
      bool valid = half ? (j >= 2) : (j < 50);
      aW[j] = valid ? A256[row * SD + col] : 0.f;
    }
  }
  if (tid < SD) X[0][tid] = use_c0 ? c0[tid] : 0.f;
  for (int b = 0; b < 255; ++b) {
    if ((b & 63) == 0) {
      __syncthreads();
      for (int i = tid; i < 1600; i += 256)
        ((float4*)sc)[i] = ((const float4*)(Send + b * SD))[i];
    }
    __syncthreads();
    if (tid < 200) {
      const float4* cb = (const float4*)(&X[b][0]) + half * 12;
      float p0 = 0.f, p1 = 0.f, p2 = 0.f, p3 = 0.f;
      #pragma unroll
      for (int i = 0; i < 13; ++i) {
        float4 c4 = cb[i];
        p0 = fmaf(aW[4 * i + 0], c4.x, p0);
        p1 = fmaf(aW[4 * i + 1], c4.y, p1);
        p2 = fmaf(aW[4 * i + 2], c4.z, p2);
        p3 = fmaf(aW[4 * i + 3], c4.w, p3);
      }
      float acc = (p0 + p1) + (p2 + p3);
      if (half == 0) acc += sc[(b & 63) * SD + row];
      acc = dpp_xor1_add(acc);
      if (half == 0) X[b + 1][row] = acc;
    }
  }
  __syncthreads();
  for (int i = tid; i < 6400; i += 256) ((float4*)Xout)[i] = ((const float4*)X)[i];
}

// ---------- K4: sequential core ----------
__global__ __launch_bounds__(256, 1) void k4_core(
    const float* __restrict__ qbuf, const float* __restrict__ A8w,
    const float* __restrict__ Pws, const float* __restrict__ Gws,
    const float* __restrict__ Qws, float* __restrict__ hbuf) {
  __shared__ __align__(16) float zwin[16 * 8];
  __shared__ __align__(16) float hring[16 * 8];
  __shared__ __align__(16) float basering[16 * 8];
  __shared__ __align__(16) float rbuf[2][100];
  const int tid = threadIdx.x;
  const int wave = tid >> 6;
  const int lane = tid & 63;

  for (int i = tid; i < 128; i += 256) { zwin[i] = 0.f; hring[i] = 0.f; }
  if (tid < 200) ((float*)rbuf)[tid] = 0.f;

  if (wave == 0) {
    // ---- wave 0: critical quad + lag-window conv + h flush ----
    float G0p[16];
    float Gc1[8], Gc2[8];
    int k1 = 0, k2 = 0, ci = 0;
    if (lane < 4) {
      const int q = lane;
      int perm[8] = {2 * q,       2 * q + 1,       2 * (q ^ 1), 2 * (q ^ 1) + 1,
                     2 * (q ^ 2), 2 * (q ^ 2) + 1, 2 * (q ^ 3), 2 * (q ^ 3) + 1};
      #pragma unroll
      for (int c = 0; c < 8; ++c) {
        G0p[c] = Gws[(2 * q) * 8 + perm[c]];
        G0p[8 + c] = Gws[(2 * q + 1) * 8 + perm[c]];
      }
    } else if (lane >= 8) {
      ci = lane & 7;
      k1 = lane >> 3;   // 1..7
      k2 = k1 + 7;      // 8..14
      #pragma unroll
      for (int c = 0; c < 8; ++c) {
        Gc1[c] = Gws[k1 * 64 + ci * 8 + c];
        Gc2[c] = Gws[k2 * 64 + ci * 8 + c];
      }
    }
    __syncthreads();  // matches other waves' init barrier
    float cur_a = 0.f, cur_b = 0.f;
    for (int m = 0; m < 8192; ++m) {
      if (lane >= 4 && lane < 8 && m > 0) {
        const int g = lane - 4;
        const float* src = hring + ((m - 1) & 1) * 64 + g * 16;
        float4* dst = (float4*)(hbuf + (size_t)(m - 1) * 64 + g * 16);
        dst[0] = *(const float4*)(src);
        dst[1] = *(const float4*)(src + 4);
        dst[2] = *(const float4*)(src + 8);
        dst[3] = *(const float4*)(src + 12);
      }
      #pragma unroll
      for (int tt = 0; tt < 8; ++tt) {
        const int t = m * 8 + tt;
        if (lane < 4) {
          float hg0 = cur_a, hg1 = cur_b;
          float hg2 = dppq<0xB1>(cur_a), hg3 = dppq<0xB1>(cur_b);
          float hg4 = dppq<0x4E>(cur_a), hg5 = dppq<0x4E>(cur_b);
          float hg6 = dppq<0x4E>(hg2), hg7 = dppq<0x4E>(hg3);
          const int sl = t & 15;
          float2 zw = *(float2*)&zwin[sl * 8 + 2 * lane];
          *(float2*)&zwin[sl * 8 + 2 * lane] = make_float2(0.f, 0.f);
          float2 ba = *(float2*)&basering[sl * 8 + 2 * lane];
          float za = ba.x + zw.x;
          float zb = ba.y + zw.y;
          za = fmaf(G0p[0], hg0, za); za = fmaf(G0p[1], hg1, za);
          za = fmaf(G0p[2], hg2, za); za = fmaf(G0p[3], hg3, za);
          za = fmaf(G0p[4], hg4, za); za = fmaf(G0p[5], hg5, za);
          za = fmaf(G0p[6], hg6, za); za = fmaf(G0p[7], hg7, za);
          zb = fmaf(G0p[8], hg0, zb); zb = fmaf(G0p[9], hg1, zb);
          zb = fmaf(G0p[10], hg2, zb); zb = fmaf(G0p[11], hg3, zb);
          zb = fmaf(G0p[12], hg4, zb); zb = fmaf(G0p[13], hg5, zb);
          zb = fmaf(G0p[14], hg6, zb); zb = fmaf(G0p[15], hg7, zb);
          cur_a = tanh_fast(za);
          cur_b = tanh_fast(zb);
          *(float2*)&hring[sl * 8 + 2 * lane] = make_float2(cur_a, cur_b);
        } else if (lane >= 8) {
          const float* h8 = hring + ((t - 1) & 15) * 8;
          float4 ha = *(const float4*)h8;
          float4 hb = *(const float4*)(h8 + 4);
          float s1 = Gc1[0] * ha.x;
          s1 = fmaf(Gc1[1], ha.y, s1); s1 = fmaf(Gc1[2], ha.z, s1);
          s1 = fmaf(Gc1[3], ha.w, s1); s1 = fmaf(Gc1[4], hb.x, s1);
          s1 = fmaf(Gc1[5], hb.y, s1); s1 = fmaf(Gc1[6], hb.z, s1);
          s1 = fmaf(Gc1[7], hb.w, s1);
          float s2 = Gc2[0] * ha.x;
          s2 = fmaf(Gc2[1], ha.y, s2); s2 = fmaf(Gc2[2], ha.z, s2);
          s2 = fmaf(Gc2[3], ha.w, s2); s2 = fmaf(Gc2[4], hb.x, s2);
          s2 = fmaf(Gc2[5], hb.y, s2); s2 = fmaf(Gc2[6], hb.z, s2);
          s2 = fmaf(Gc2[7], hb.w, s2);
          // lag-k2 term only valid once its source step is inside the
          // target's (block-1) horizon: include iff ((t+k2)&7) >= k2-7
          if (((t + k2) & 7) < (k2 - 7)) s2 = 0.f;
          zwin[((t + k1) & 15) * 8 + ci] += s1;
          zwin[((t + k2) & 15) * 8 + ci] += s2;
        }
      }
      __syncthreads();
    }
    if (lane >= 4 && lane < 8) {  // flush h of final block
      const int g = lane - 4;
      const float* src = hring + 64 + g * 16;  // 8191&1 = 1
      float4* dst = (float4*)(hbuf + (size_t)8191 * 64 + g * 16);
      dst[0] = *(const float4*)(src);
      dst[1] = *(const float4*)(src + 4);
      dst[2] = *(const float4*)(src + 8);
      dst[3] = *(const float4*)(src + 12);
    }
  } else if (wave == 1 || wave == 3) {
    // ---- r-advance: r_m = A^8 r_{m-1} + sum_i Q_i h[(m-1)*8+i] ----
    const int rrow = (wave == 1) ? lane : 64 + lane;
    float A8row[100];
    float Qrow[64];
    if (rrow < 100) {
      #pragma unroll
      for (int i = 0; i < 25; ++i)
        *(float4*)&A8row[4 * i] = ((const float4*)(A8w + rrow * 100))[i];
      #pragma unroll
      for (int i = 0; i < 8; ++i)
        #pragma unroll
        for (int c = 0; c < 8; ++c) Qrow[i * 8 + c] = Qws[i * 800 + rrow * 8 + c];
    }
    __syncthreads();
    for (int m = 0; m < 8192; ++m) {
      if (rrow < 100) {
        const float* rp = rbuf[(m + 1) & 1];
        float p0 = 0.f, p1 = 0.f, p2 = 0.f, p3 = 0.f;
        #pragma unroll
        for (int i = 0; i < 25; ++i) {
          float4 r4 = ((const float4*)rp)[i];
          p0 = fmaf(A8row[4 * i + 0], r4.x, p0);
          p1 = fmaf(A8row[4 * i + 1], r4.y, p1);
          p2 = fmaf(A8row[4 * i + 2], r4.z, p2);
          p3 = fmaf(A8row[4 * i + 3], r4.w, p3);
        }
        float acc = (p0 + p1) + (p2 + p3);
        const float* hb = hring + ((m - 1) & 1) * 64;
        #pragma unroll
        for (int i = 0; i < 8; ++i) {
          float4 x0 = *(const float4*)(hb + i * 8);
          float4 x1 = *(const float4*)(hb + i * 8 + 4);
          acc = fmaf(Qrow[i * 8 + 0], x0.x, acc);
          acc = fmaf(Qrow[i * 8 + 1], x0.y, acc);
          acc = fmaf(Qrow[i * 8 + 2], x0.z, acc);
          acc = fmaf(Qrow[i * 8 + 3], x0.w, acc);
          acc = fmaf(Qrow[i * 8 + 4], x1.x, acc);
          acc = fmaf(Qrow[i * 8 + 5], x1.y, acc);
          acc = fmaf(Qrow[i * 8 + 6], x1.z, acc);
          acc = fmaf(Qrow[i * 8 + 7], x1.w, acc);
        }
        rbuf[m & 1][rrow] = acc;
      }
      __syncthreads();
    }
  } else {
    // ---- wave 2: base for block m+1 = q + P_{16+wj} r_{m-1} + G-terms ----
    const int wj = lane >> 3, wi = lane & 7;
    float Prow[100];
    float Gw2[64];
    #pragma unroll
    for (int i = 0; i < 25; ++i)
      *(float4*)&Prow[4 * i] = ((const float4*)(Pws + wj * 800 + wi * 100))[i];
    #pragma unroll
    for (int jj = 0; jj < 8; ++jj)
      #pragma unroll
      for (int c = 0; c < 8; ++c)
        Gw2[jj * 8 + c] = Gws[(15 + wj - jj) * 64 + wi * 8 + c];
    basering[wj * 8 + wi] = qbuf[wj * 8 + wi];  // block-0 base = q
    __syncthreads();
    for (int m = 0; m < 8192; ++m) {
      const int tp = (m + 1) * 8 + wj;
      float qv = qbuf[(size_t)tp * 8 + wi];
      const float* rp = rbuf[(m + 1) & 1];
      float p0 = 0.f, p1 = 0.f, p2 = 0.f, p3 = 0.f;
      #pragma unroll
      for (int i = 0; i < 25; ++i) {
        float4 r4 = ((const float4*)rp)[i];
        p0 = fmaf(Prow[4 * i + 0], r4.x, p0);
        p1 = fmaf(Prow[4 * i + 1], r4.y, p1);
        p2 = fmaf(Prow[4 * i + 2], r4.z, p2);
        p3 = fmaf(Prow[4 * i + 3], r4.w, p3);
      }
      float tail = (p0 + p1) + (p2 + p3);
      const float* hb = hring + ((m - 1) & 1) * 64;
      float gs = 0.f;
      #pragma unroll
      for (int jj = 0; jj < 8; ++jj) {
        float4 x0 = *(const float4*)(hb + jj * 8);
        float4 x1 = *(const float4*)(hb + jj * 8 + 4);
        gs = fmaf(Gw2[jj * 8 + 0], x0.x, gs);
        gs = fmaf(Gw2[jj * 8 + 1], x0.y, gs);
        gs = fmaf(Gw2[jj * 8 + 2], x0.z, gs);
        gs = fmaf(Gw2[jj * 8 + 3], x0.w, gs);
        gs = fmaf(Gw2[jj * 8 + 4], x1.x, gs);
        gs = fmaf(Gw2[jj * 8 + 5], x1.y, gs);
        gs = fmaf(Gw2[jj * 8 + 6], x1.z, gs);
        gs = fmaf(Gw2[jj * 8 + 7], x1.w, gs);
      }
      basering[(tp & 15) * 8 + wi] = qv + tail + gs;
      __syncthreads();
    }
  }
}

// ---------- launch ----------
extern "C" void kernel_launch(void* const* d_in, const int* in_sizes, int n_in,
                              void* d_out, int out_size, void* d_ws, size_t ws_size,
                              hipStream_t stream) {
  const float* c0 = (const float*)d_in[0];
  const float* w  = (const float*)d_in[1];
  const float* u  = (const float*)d_in[2];
  const float* A  = (const float*)d_in[3];
  const float* Bw = (const float*)d_in[4];
  const float* W1 = (const float*)d_in[5];
  const float* b1 = (const float*)d_in[6];
  const float* W2 = (const float*)d_in[7];
  const float* b2 = (const float*)d_in[8];
  const int* obs  = (const int*)d_in[9];
  float* out_c = (float*)d_out;
  float* out_y = out_c + (size_t)T_STEPS * SD;

  float* wsf = (float*)d_ws;
  float* A8    = wsf;                 // 10000
  float* A256  = wsf + 10000;         // 10000
  float* Pws   = wsf + 20000;         // 8*800
  float* Gws   = wsf + 26400;         // 23*64
  float* Qws   = wsf + 27872;         // 8*800
  float* Send  = wsf + 34272;         // 256*100
  float* X     = wsf + 59872;         // 256*100
  float* qbuf  = wsf + 85472;         // (T+16)*8
  float* hbuf  = wsf + 609888;        // T*8 + 64
  float* SendR = wsf + 1134240;       // 256*100
  float* XR    = wsf + 1159840;       // 256*100

  hipLaunchKernelGGL(k0_setup, dim3(1), dim3(256), 0, stream,
                     A, W1, W2, A8, A256, Pws, Gws, Qws);
  hipLaunchKernelGGL(k_rollout<0>, dim3(256), dim3(256), 0, stream,
                     A, Bw, b2, u, w, (const float*)nullptr, (const float*)nullptr,
                     (const float*)nullptr, (const float*)nullptr, (const float*)nullptr,
                     (const float*)nullptr, Send, (float*)nullptr, (float*)nullptr,
                     (const int*)nullptr, (float*)nullptr);
  hipLaunchKernelGGL(k_scan, dim3(1), dim3(256), 0, stream, A256, Send, c0, 1, X);
  hipLaunchKernelGGL(k_rollout<1>, dim3(256), dim3(256), 0, stream,
                     A, Bw, b2, u, w, (const float*)nullptr, (const float*)nullptr,
                     W1, b1, c0, X, (float*)nullptr, out_c, qbuf,
                     (const int*)nullptr, (float*)nullptr);
  hipLaunchKernelGGL(k4_core, dim3(1), dim3(256), 0, stream,
                     qbuf, A8, Pws, Gws, Qws, hbuf);
  hipLaunchKernelGGL(k_rollout<2>, dim3(256), dim3(256), 0, stream,
                     A, (const float*)nullptr, (const float*)nullptr,
                     (const float*)nullptr, (const float*)nullptr, W2, hbuf,
                     (const float*)nullptr, (const float*)nullptr, (const float*)nullptr,
                     (const float*)nullptr, SendR, (float*)nullptr, (float*)nullptr,
                     (const int*)nullptr, (float*)nullptr);
  hipLaunchKernelGGL(k_scan, dim3(1), dim3(256), 0, stream, A256, SendR,
                     (const float*)nullptr, 0, XR);
  hipLaunchKernelGGL(k_rollout<3>, dim3(256), dim3(256), 0, stream,
                     A, (const float*)nullptr, (const float*)nullptr,
                     (const float*)nullptr, (const float*)nullptr, W2, hbuf,
                     (const float*)nullptr, (const float*)nullptr, (const float*)nullptr,
                     XR, (float*)nullptr, out_c, (float*)nullptr, obs, out_y);
}